// Round 2
// baseline (1616.257 us; speedup 1.0000x reference)
//
#include <hip/hip_runtime.h>
#include <hip/hip_bf16.h>
#include <cstdint>
#include <cstddef>

// ---------------------------------------------------------------------------
// DeepseekMoE round 4:
//  - counted-vmcnt depth-2 pipeline (3 LDS buffers, raw s_barrier, never
//    vmcnt(0) in steady state)  [T3+T4]
//  - LDS XOR swizzle via inverse-permuted global source + permuted reads
//    (rule 21: linear global_load_lds dest)                       [T2]
//  - flattened 1D grid, mt-fastest, m157 XCD-chunked swizzle so M-tile
//    siblings sharing a B-panel co-reside on one XCD's L2          [T1]
//  - keeps: bf16 preconvert, merged shared expert, slot_out + combine
//    (no atomics)
// ---------------------------------------------------------------------------

typedef __bf16 bf16;
typedef __bf16 bf16x8 __attribute__((ext_vector_type(8)));
typedef float  f32x4  __attribute__((ext_vector_type(4)));

constexpr int Hdim  = 2048;
constexpr int Idim  = 1408;
constexpr int NE    = 16;
constexpr int TOPK  = 6;
constexpr int ISdim = 2816;
constexpr int Ttok  = 2048;
constexpr int BMT   = 256;            // M tile for both grouped GEMMs
// sum over experts of ceil(cnt_e/256)*256 <= 12288 + 16*255 = 16368
constexpr int MAX_SLOTS = 16384;

// gateup grid: routed 16e * 22x * 8mt = 2816, shared 44x * 8mt = 352
constexpr int GU_R    = 2816;
constexpr int GU_GRID = 3168;          // divisible by 8
constexpr int GU_CHNK = GU_GRID / 8;   // 396
// down grid: routed 16e * 16x * 8mt = 2048, shared 16x * 8mt = 128
constexpr int DN_R    = 2048;
constexpr int DN_GRID = 2176;          // divisible by 8
constexpr int DN_CHNK = DN_GRID / 8;   // 272

__device__ __forceinline__ void gll16(const void* g, void* l) {
  __builtin_amdgcn_global_load_lds((__attribute__((address_space(1))) void*)(g),
                                   (__attribute__((address_space(3))) void*)(l),
                                   16, 0, 0);
}

#define WAITVM(N) do { asm volatile("s_waitcnt vmcnt(" #N ")" ::: "memory"); \
                       __builtin_amdgcn_sched_barrier(0); } while (0)

// --------------------------- small kernels ---------------------------------

__global__ void init_kernel(int* cnt, int* fill, int* tok_of_slot, float* wt_of_slot) {
  int i = blockIdx.x * 256 + threadIdx.x;
  if (i < NE) { cnt[i] = 0; fill[i] = 0; }
  if (i < MAX_SLOTS) { tok_of_slot[i] = -1; wt_of_slot[i] = 0.f; }
}

// fp32 -> bf16, 8 elems/thread
__global__ void cvt_kernel(const float* __restrict__ src, bf16* __restrict__ dst, int n8) {
  int i = blockIdx.x * 256 + threadIdx.x;
  if (i >= n8) return;
  f32x4 f0 = *(const f32x4*)(src + (size_t)i * 8);
  f32x4 f1 = *(const f32x4*)(src + (size_t)i * 8 + 4);
  bf16x8 v;
#pragma unroll
  for (int j = 0; j < 4; j++) { v[j] = (bf16)f0[j]; v[j + 4] = (bf16)f1[j]; }
  *(bf16x8*)(dst + (size_t)i * 8) = v;
}

__global__ void router_kernel(const float* __restrict__ x, const float* __restrict__ gw,
                              int* __restrict__ sel_e, float* __restrict__ sel_w,
                              int* __restrict__ cnt) {
  int t = blockIdx.x;
  int lane = threadIdx.x;
  const float* xr = x + (size_t)t * Hdim;
  float acc[NE];
#pragma unroll
  for (int e = 0; e < NE; e++) acc[e] = 0.f;
  for (int h = lane; h < Hdim; h += 64) {
    float xv = xr[h];
#pragma unroll
    for (int e = 0; e < NE; e++) acc[e] += xv * gw[e * Hdim + h];
  }
#pragma unroll
  for (int e = 0; e < NE; e++) {
#pragma unroll
    for (int off = 32; off > 0; off >>= 1) acc[e] += __shfl_xor(acc[e], off, 64);
  }
  if (lane == 0) {
    float m = acc[0];
#pragma unroll
    for (int e = 1; e < NE; e++) m = fmaxf(m, acc[e]);
    float p[NE]; float s = 0.f;
#pragma unroll
    for (int e = 0; e < NE; e++) { p[e] = __expf(acc[e] - m); s += p[e]; }
    float inv = 1.f / s;
    bool used[NE];
#pragma unroll
    for (int e = 0; e < NE; e++) used[e] = false;
    for (int k = 0; k < TOPK; k++) {   // strict > keeps lowest index on ties (lax.top_k)
      int best = 0; float bv = -1.f;
      for (int e = 0; e < NE; e++) if (!used[e] && p[e] > bv) { bv = p[e]; best = e; }
      used[best] = true;
      sel_e[t * TOPK + k] = best;
      sel_w[t * TOPK + k] = bv * inv;   // NORM_TOPK_PROB=False -> raw softmax prob
      atomicAdd(&cnt[best], 1);
    }
  }
}

__global__ void scan_kernel(const int* __restrict__ cnt, int* __restrict__ pbase,
                            int* __restrict__ mtiles) {
  if (threadIdx.x == 0 && blockIdx.x == 0) {
    int pb = 0;
    for (int e = 0; e < NE; e++) {
      pbase[e] = pb;
      int mt = (cnt[e] + BMT - 1) / BMT;
      mtiles[e] = mt;
      pb += mt * BMT;
    }
  }
}

__global__ void assign_kernel(const int* __restrict__ sel_e, const float* __restrict__ sel_w,
                              const int* __restrict__ pbase, int* __restrict__ fill,
                              int* __restrict__ tok_of_slot, float* __restrict__ wt_of_slot,
                              int* __restrict__ slot_of) {
  int i = blockIdx.x * 256 + threadIdx.x;
  if (i >= Ttok * TOPK) return;
  int e = sel_e[i];
  int t = i / TOPK;
  int pos = atomicAdd(&fill[e], 1);
  int slot = pbase[e] + pos;
  tok_of_slot[slot] = t;
  wt_of_slot[slot] = sel_w[i];
  slot_of[i] = slot;
}

// --------------------------- gate+up fused GEMM -----------------------------
// act[row][col] = silu(A@G^T)*(A@U^T)*rowscale.  BM=256, BN=64 per matmul,
// BK=32. Depth-2 counted-vmcnt pipeline, 3 LDS buffers, raw barriers.
// LDS bank swizzle: stage thread (srow,c) fetches global 16B-chunk
// c ^ ((srow>>1)&3) into linear slot c; readers XOR quad the same way.

__global__ __launch_bounds__(256, 2)
void gateup_kernel(const bf16* __restrict__ Abase,
                   const bf16* __restrict__ w1b, const bf16* __restrict__ sw1b,
                   bf16* __restrict__ actx, bf16* __restrict__ acts,
                   const int* __restrict__ tok_of_slot, const float* __restrict__ wt_of_slot,
                   const int* __restrict__ pbase, const int* __restrict__ mtiles) {
  constexpr int BM = BMT;
  constexpr int NQ = BM / 64;        // 4 64-row staging chunks of A
  constexpr int WROWS = BM / 4;      // 64 rows per wave
  constexpr int NI = WROWS / 16;     // 4
  constexpr int K = Hdim;
  constexpr int NT = K / 32;         // 64 K-steps

  // XCD-chunked swizzle: dispatch d -> logical l; logical order is mt-fastest
  // so the (<=8) M-tile siblings sharing one B panel sit in one XCD chunk.
  const int l = ((int)blockIdx.x & 7) * GU_CHNK + ((int)blockIdx.x >> 3);
  bool SH; int e = 0, xt, mt;
  if (l < GU_R) {
    SH = false;
    e = l / 176; int r = l - e * 176;        // 176 = 22 x-tiles * 8 mt
    xt = r >> 3; mt = r & 7;
    if (mt >= mtiles[e]) return;
  } else {
    SH = true;
    int ls = l - GU_R;                       // 352 = 44 x-tiles * 8 mt
    xt = ls >> 3; mt = ls & 7;
  }
  const bf16* Wb; bf16* C; int Isz, row0;
  if (SH) { Wb = sw1b; C = acts; Isz = ISdim; row0 = mt * BM; }
  else    { Wb = w1b + (size_t)e * 2 * Idim * Hdim; C = actx; Isz = Idim;
            row0 = pbase[e] + mt * BM; }
  const int col0 = xt * 64;

  const int tid = threadIdx.x;
  const int lane = tid & 63;
  const int wv = tid >> 6;
  const int m16 = lane & 15, quad = lane >> 4;

  __shared__ __align__(16) bf16 ldsA[3][BM * 32];
  __shared__ __align__(16) bf16 ldsG[3][64 * 32];
  __shared__ __align__(16) bf16 ldsU[3][64 * 32];

  const int srow = tid >> 2;                       // 0..63
  const int scol = ((tid & 3) ^ ((srow >> 1) & 3)) * 8;   // inverse bank swizzle

  const bf16* aptr[NQ];
#pragma unroll
  for (int q = 0; q < NQ; q++) {
    int r = row0 + q * 64 + srow;
    int tok = SH ? r : tok_of_slot[r];
    if (tok < 0) tok = 0;            // pad slot: rowscale==0 zeroes its act
    aptr[q] = Abase + (size_t)tok * K + scol;
  }
  const bf16* gptr = Wb + (size_t)(col0 + srow) * K + scol;
  const bf16* uptr = Wb + (size_t)(Isz + col0 + srow) * K + scol;

  f32x4 accg[NI][4], accu[NI][4];
#pragma unroll
  for (int i = 0; i < NI; i++)
#pragma unroll
    for (int j = 0; j < 4; j++)
#pragma unroll
      for (int r = 0; r < 4; r++) { accg[i][j][r] = 0.f; accu[i][j][r] = 0.f; }

  auto stage = [&](int b, int k) {               // 6 gll16 per thread
    gll16(gptr + k, &ldsG[b][tid * 8]);
    gll16(uptr + k, &ldsU[b][tid * 8]);
#pragma unroll
    for (int q = 0; q < NQ; q++) gll16(aptr[q] + k, &ldsA[b][q * 2048 + tid * 8]);
  };

  const int qsw8 = (quad ^ ((m16 >> 1) & 3)) * 8;   // read-side bank swizzle

  stage(0, 0);
  stage(1, 32);
#pragma unroll 1
  for (int ks = 0; ks < NT; ks++) {
    const int cur = ks % 3;
    if (ks + 2 < NT) {
      int nb = cur + 2; if (nb >= 3) nb -= 3;
      stage(nb, (ks + 2) * 32);
      WAITVM(12);                    // wait stage(ks): issued 2 steps ago
    } else if (ks + 2 == NT) {
      WAITVM(6);
    } else {
      WAITVM(0);
    }
    __builtin_amdgcn_s_barrier();    // all waves' buf[cur] loads landed
    bf16x8 af[NI], gf[4], uf[4];
#pragma unroll
    for (int i = 0; i < NI; i++)
      af[i] = *(const bf16x8*)(&ldsA[cur][(wv * WROWS + i * 16 + m16) * 32 + qsw8]);
#pragma unroll
    for (int j = 0; j < 4; j++) {
      gf[j] = *(const bf16x8*)(&ldsG[cur][(j * 16 + m16) * 32 + qsw8]);
      uf[j] = *(const bf16x8*)(&ldsU[cur][(j * 16 + m16) * 32 + qsw8]);
    }
#pragma unroll
    for (int i = 0; i < NI; i++)
#pragma unroll
      for (int j = 0; j < 4; j++) {
        accg[i][j] = __builtin_amdgcn_mfma_f32_16x16x32_bf16(af[i], gf[j], accg[i][j], 0, 0, 0);
        accu[i][j] = __builtin_amdgcn_mfma_f32_16x16x32_bf16(af[i], uf[j], accu[i][j], 0, 0, 0);
      }
    __builtin_amdgcn_s_barrier();    // all waves done reading buf[cur]
  }

#pragma unroll
  for (int i = 0; i < NI; i++) {
#pragma unroll
    for (int r = 0; r < 4; r++) {
      int grow = row0 + wv * WROWS + i * 16 + quad * 4 + r;
      float scale = SH ? 1.f : wt_of_slot[grow];
#pragma unroll
      for (int j = 0; j < 4; j++) {
        float g = accg[i][j][r];
        float u = accu[i][j][r];
        float a = g * u * scale / (1.f + __expf(-g));   // silu(g)*u*scale
        C[(size_t)grow * Isz + (col0 + j * 16 + m16)] = (bf16)a;
      }
    }
  }
}

// --------------------------- down-proj GEMM ---------------------------------
// BM=256, BN=128, BK=32; same depth-2 counted-vmcnt pipeline + swizzles.
// Routed: plain store to slot_out[slot][H]; shared: plain store to out[t][H].

__global__ __launch_bounds__(256, 2)
void down_kernel(const bf16* __restrict__ actx, const bf16* __restrict__ acts,
                 const bf16* __restrict__ w2b, const bf16* __restrict__ sw2b,
                 float* __restrict__ slot_out, float* __restrict__ out,
                 const int* __restrict__ pbase, const int* __restrict__ mtiles) {
  constexpr int BM = BMT;
  constexpr int NQ = BM / 64;
  constexpr int WROWS = BM / 4;
  constexpr int NI = WROWS / 16;

  const int l = ((int)blockIdx.x & 7) * DN_CHNK + ((int)blockIdx.x >> 3);
  bool SH; int e = 0, xt, mt;
  if (l < DN_R) {
    SH = false;
    e = l >> 7; int r = l & 127;             // 128 = 16 x-tiles * 8 mt
    xt = r >> 3; mt = r & 7;
    if (mt >= mtiles[e]) return;
  } else {
    SH = true;
    int ls = l - DN_R;                       // 128 = 16 x-tiles * 8 mt
    xt = ls >> 3; mt = ls & 7;
  }
  const bf16* A; const bf16* Wb; float* dst; int K, row0;
  if (SH) { A = acts; Wb = sw2b; dst = out; K = ISdim; row0 = mt * BM; }
  else    { A = actx; Wb = w2b + (size_t)e * Hdim * Idim; dst = slot_out; K = Idim;
            row0 = pbase[e] + mt * BM; }
  const int NT = K / 32;                     // 88 (shared) or 44 (routed)
  const int col0 = xt * 128;

  const int tid = threadIdx.x;
  const int lane = tid & 63;
  const int wv = tid >> 6;
  const int m16 = lane & 15, quad = lane >> 4;

  __shared__ __align__(16) bf16 ldsA[3][BM * 32];
  __shared__ __align__(16) bf16 ldsB[3][128 * 32];

  const int srow = tid >> 2;
  const int scol = ((tid & 3) ^ ((srow >> 1) & 3)) * 8;

  const bf16* aptr[NQ];
#pragma unroll
  for (int q = 0; q < NQ; q++)
    aptr[q] = A + (size_t)(row0 + q * 64 + srow) * K + scol;
  const bf16* bptr[2];
#pragma unroll
  for (int q = 0; q < 2; q++)
    bptr[q] = Wb + (size_t)(col0 + q * 64 + srow) * K + scol;

  f32x4 acc[NI][8];
#pragma unroll
  for (int i = 0; i < NI; i++)
#pragma unroll
    for (int j = 0; j < 8; j++)
#pragma unroll
      for (int r = 0; r < 4; r++) acc[i][j][r] = 0.f;

  auto stage = [&](int b, int k) {           // 6 gll16 per thread
#pragma unroll
    for (int q = 0; q < 2; q++) gll16(bptr[q] + k, &ldsB[b][q * 2048 + tid * 8]);
#pragma unroll
    for (int q = 0; q < NQ; q++) gll16(aptr[q] + k, &ldsA[b][q * 2048 + tid * 8]);
  };

  const int qsw8 = (quad ^ ((m16 >> 1) & 3)) * 8;

  stage(0, 0);
  stage(1, 32);
#pragma unroll 1
  for (int ks = 0; ks < NT; ks++) {
    const int cur = ks % 3;
    if (ks + 2 < NT) {
      int nb = cur + 2; if (nb >= 3) nb -= 3;
      stage(nb, (ks + 2) * 32);
      WAITVM(12);
    } else if (ks + 2 == NT) {
      WAITVM(6);
    } else {
      WAITVM(0);
    }
    __builtin_amdgcn_s_barrier();
    bf16x8 af[NI], bfr[8];
#pragma unroll
    for (int i = 0; i < NI; i++)
      af[i] = *(const bf16x8*)(&ldsA[cur][(wv * WROWS + i * 16 + m16) * 32 + qsw8]);
#pragma unroll
    for (int j = 0; j < 8; j++)
      bfr[j] = *(const bf16x8*)(&ldsB[cur][(j * 16 + m16) * 32 + qsw8]);
#pragma unroll
    for (int i = 0; i < NI; i++)
#pragma unroll
      for (int j = 0; j < 8; j++)
        acc[i][j] = __builtin_amdgcn_mfma_f32_16x16x32_bf16(af[i], bfr[j], acc[i][j], 0, 0, 0);
    __builtin_amdgcn_s_barrier();
  }

#pragma unroll
  for (int i = 0; i < NI; i++) {
#pragma unroll
    for (int r = 0; r < 4; r++) {
      int grow = row0 + wv * WROWS + i * 16 + quad * 4 + r;
      float* orow = dst + (size_t)grow * Hdim;   // slot row (routed) or token row (shared)
#pragma unroll
      for (int j = 0; j < 8; j++) orow[col0 + j * 16 + m16] = acc[i][j][r];
    }
  }
}

// --------------------------- combine ----------------------------------------
// out[t] (already holds shared-path result) += sum_k slot_out[slot_of[t][k]].

__global__ void combine_kernel(const float* __restrict__ slot_out,
                               const int* __restrict__ slot_of,
                               float* __restrict__ out) {
  const int t = blockIdx.x;
  const int c = threadIdx.x * 8;
  float* op = out + (size_t)t * Hdim + c;
  f32x4 a0 = *(const f32x4*)op;
  f32x4 a1 = *(const f32x4*)(op + 4);
#pragma unroll
  for (int k = 0; k < TOPK; k++) {
    int s = slot_of[t * TOPK + k];
    const float* sp = slot_out + (size_t)s * Hdim + c;
    f32x4 b0 = *(const f32x4*)sp;
    f32x4 b1 = *(const f32x4*)(sp + 4);
    a0 += b0; a1 += b1;
  }
  *(f32x4*)op = a0;
  *(f32x4*)(op + 4) = a1;
}

// --------------------------- launch ----------------------------------------

extern "C" void kernel_launch(void* const* d_in, const int* in_sizes, int n_in,
                              void* d_out, int out_size, void* d_ws, size_t ws_size,
                              hipStream_t stream) {
  (void)in_sizes; (void)n_in; (void)out_size; (void)ws_size;
  const float* x   = (const float*)d_in[0];
  const float* gw  = (const float*)d_in[1];
  const float* w1  = (const float*)d_in[2];
  const float* w2  = (const float*)d_in[3];
  const float* sw1 = (const float*)d_in[4];
  const float* sw2 = (const float*)d_in[5];
  float* out = (float*)d_out;

  char* ws = (char*)d_ws;
  size_t off = 0;
  auto alloc = [&](size_t bytes) -> void* {
    void* p = ws + off;
    off += (bytes + 255) & ~(size_t)255;
    return p;
  };
  int*   cnt   = (int*)alloc(NE * 4);
  int*   fill  = (int*)alloc(NE * 4);
  int*   pbase = (int*)alloc(NE * 4);
  int*   mtl   = (int*)alloc(NE * 4);
  int*   sel_e = (int*)alloc((size_t)Ttok * TOPK * 4);
  float* sel_w = (float*)alloc((size_t)Ttok * TOPK * 4);
  int*   slotf = (int*)alloc((size_t)Ttok * TOPK * 4);
  int*   tok   = (int*)alloc((size_t)MAX_SLOTS * 4);
  float* wt    = (float*)alloc((size_t)MAX_SLOTS * 4);
  bf16*  xb    = (bf16*)alloc((size_t)Ttok * Hdim * 2);
  bf16*  actx  = (bf16*)alloc((size_t)MAX_SLOTS * Idim * 2);   // expert activations
  bf16*  acts  = (bf16*)alloc((size_t)Ttok * ISdim * 2);       // shared activations

  const size_t n_w1  = (size_t)NE * 2 * Idim * Hdim;   // 92.3M
  const size_t n_w2  = (size_t)NE * Hdim * Idim;       // 46.1M
  const size_t n_sw1 = (size_t)2 * ISdim * Hdim;       // 11.5M
  const size_t n_sw2 = (size_t)Hdim * ISdim;           // 5.8M
  bf16* w1b  = (bf16*)alloc(n_w1 * 2);    // 184.6 MB
  bf16* w2b  = (bf16*)alloc(n_w2 * 2);
  bf16* sw1b = (bf16*)alloc(n_sw1 * 2);
  bf16* sw2b = (bf16*)alloc(n_sw2 * 2);
  // slot_out (MAX_SLOTS x H fp32 = 134 MB) aliases w1b (184.6 MB): w1b is dead
  // after the gateup launch; the down launch writing slot_out is in-stream after.
  float* slot_out = (float*)w1b;

  init_kernel<<<(MAX_SLOTS + 255) / 256, 256, 0, stream>>>(cnt, fill, tok, wt);
  cvt_kernel<<<((int)(Ttok * (size_t)Hdim / 8) + 255) / 256, 256, 0, stream>>>(x, xb, Ttok * Hdim / 8);
  router_kernel<<<Ttok, 64, 0, stream>>>(x, gw, sel_e, sel_w, cnt);
  scan_kernel<<<1, 64, 0, stream>>>(cnt, pbase, mtl);
  assign_kernel<<<(Ttok * TOPK + 255) / 256, 256, 0, stream>>>(sel_e, sel_w, pbase, fill, tok, wt, slotf);

  cvt_kernel<<<((int)(n_w1 / 8) + 255) / 256, 256, 0, stream>>>(w1, w1b, (int)(n_w1 / 8));
  cvt_kernel<<<((int)(n_w2 / 8) + 255) / 256, 256, 0, stream>>>(w2, w2b, (int)(n_w2 / 8));
  cvt_kernel<<<((int)(n_sw1 / 8) + 255) / 256, 256, 0, stream>>>(sw1, sw1b, (int)(n_sw1 / 8));
  cvt_kernel<<<((int)(n_sw2 / 8) + 255) / 256, 256, 0, stream>>>(sw2, sw2b, (int)(n_sw2 / 8));

  gateup_kernel<<<GU_GRID, 256, 0, stream>>>(xb, w1b, sw1b, actx, acts, tok, wt, pbase, mtl);
  down_kernel<<<DN_GRID, 256, 0, stream>>>(actx, acts, w2b, sw2b, slot_out, out, pbase, mtl);
  combine_kernel<<<Ttok, Hdim / 8, 0, stream>>>(slot_out, slotf, out);
}

// Round 3
// 1612.384 us; speedup vs baseline: 1.0024x; 1.0024x over previous
//
#include <hip/hip_runtime.h>
#include <hip/hip_bf16.h>
#include <cstdint>
#include <cstddef>

// ---------------------------------------------------------------------------
// DeepseekMoE round 5: recombination of proven pieces.
//  - GEMM loop reverted to the round-0 winner: SINGLE 24 KB LDS buffer,
//    stage -> __syncthreads -> compute -> __syncthreads (max wave residency;
//    rounds 3/4 showed time tracks occupancy inversely: 24KB/245us,
//    48KB/371us, 72KB/447us -- wave-level TLP is the latency hider here)
//  - kept from round 4 (both proven at counter level, LDS-neutral):
//      * source+read XOR bank swizzle  (SQ_LDS_BANK_CONFLICT 1.97e7 -> 0)
//      * 1D XCD-chunked grid, mt-fastest (FETCH_SIZE 375 -> 183 MB; B-panel
//        re-sweep served from L2 -> barrier drain waits ~200cy not ~700cy)
//  - kept: bf16 preconvert, merged shared expert, slot_out+combine (no atomics)
// ---------------------------------------------------------------------------

typedef __bf16 bf16;
typedef __bf16 bf16x8 __attribute__((ext_vector_type(8)));
typedef float  f32x4  __attribute__((ext_vector_type(4)));

constexpr int Hdim  = 2048;
constexpr int Idim  = 1408;
constexpr int NE    = 16;
constexpr int TOPK  = 6;
constexpr int ISdim = 2816;
constexpr int Ttok  = 2048;
constexpr int BMT   = 256;            // M tile for both grouped GEMMs
// sum over experts of ceil(cnt_e/256)*256 <= 12288 + 16*255 = 16368
constexpr int MAX_SLOTS = 16384;

// gateup grid: routed 16e * 22x * 8mt = 2816, shared 44x * 8mt = 352
constexpr int GU_R    = 2816;
constexpr int GU_GRID = 3168;          // divisible by 8
constexpr int GU_CHNK = GU_GRID / 8;   // 396
// down grid: routed 16e * 16x * 8mt = 2048, shared 16x * 8mt = 128
constexpr int DN_R    = 2048;
constexpr int DN_GRID = 2176;          // divisible by 8
constexpr int DN_CHNK = DN_GRID / 8;   // 272

__device__ __forceinline__ void gll16(const void* g, void* l) {
  __builtin_amdgcn_global_load_lds((__attribute__((address_space(1))) void*)(g),
                                   (__attribute__((address_space(3))) void*)(l),
                                   16, 0, 0);
}

// --------------------------- small kernels ---------------------------------

__global__ void init_kernel(int* cnt, int* fill, int* tok_of_slot, float* wt_of_slot) {
  int i = blockIdx.x * 256 + threadIdx.x;
  if (i < NE) { cnt[i] = 0; fill[i] = 0; }
  if (i < MAX_SLOTS) { tok_of_slot[i] = -1; wt_of_slot[i] = 0.f; }
}

// fp32 -> bf16, 8 elems/thread
__global__ void cvt_kernel(const float* __restrict__ src, bf16* __restrict__ dst, int n8) {
  int i = blockIdx.x * 256 + threadIdx.x;
  if (i >= n8) return;
  f32x4 f0 = *(const f32x4*)(src + (size_t)i * 8);
  f32x4 f1 = *(const f32x4*)(src + (size_t)i * 8 + 4);
  bf16x8 v;
#pragma unroll
  for (int j = 0; j < 4; j++) { v[j] = (bf16)f0[j]; v[j + 4] = (bf16)f1[j]; }
  *(bf16x8*)(dst + (size_t)i * 8) = v;
}

__global__ void router_kernel(const float* __restrict__ x, const float* __restrict__ gw,
                              int* __restrict__ sel_e, float* __restrict__ sel_w,
                              int* __restrict__ cnt) {
  int t = blockIdx.x;
  int lane = threadIdx.x;
  const float* xr = x + (size_t)t * Hdim;
  float acc[NE];
#pragma unroll
  for (int e = 0; e < NE; e++) acc[e] = 0.f;
  for (int h = lane; h < Hdim; h += 64) {
    float xv = xr[h];
#pragma unroll
    for (int e = 0; e < NE; e++) acc[e] += xv * gw[e * Hdim + h];
  }
#pragma unroll
  for (int e = 0; e < NE; e++) {
#pragma unroll
    for (int off = 32; off > 0; off >>= 1) acc[e] += __shfl_xor(acc[e], off, 64);
  }
  if (lane == 0) {
    float m = acc[0];
#pragma unroll
    for (int e = 1; e < NE; e++) m = fmaxf(m, acc[e]);
    float p[NE]; float s = 0.f;
#pragma unroll
    for (int e = 0; e < NE; e++) { p[e] = __expf(acc[e] - m); s += p[e]; }
    float inv = 1.f / s;
    bool used[NE];
#pragma unroll
    for (int e = 0; e < NE; e++) used[e] = false;
    for (int k = 0; k < TOPK; k++) {   // strict > keeps lowest index on ties (lax.top_k)
      int best = 0; float bv = -1.f;
      for (int e = 0; e < NE; e++) if (!used[e] && p[e] > bv) { bv = p[e]; best = e; }
      used[best] = true;
      sel_e[t * TOPK + k] = best;
      sel_w[t * TOPK + k] = bv * inv;   // NORM_TOPK_PROB=False -> raw softmax prob
      atomicAdd(&cnt[best], 1);
    }
  }
}

__global__ void scan_kernel(const int* __restrict__ cnt, int* __restrict__ pbase,
                            int* __restrict__ mtiles) {
  if (threadIdx.x == 0 && blockIdx.x == 0) {
    int pb = 0;
    for (int e = 0; e < NE; e++) {
      pbase[e] = pb;
      int mt = (cnt[e] + BMT - 1) / BMT;
      mtiles[e] = mt;
      pb += mt * BMT;
    }
  }
}

__global__ void assign_kernel(const int* __restrict__ sel_e, const float* __restrict__ sel_w,
                              const int* __restrict__ pbase, int* __restrict__ fill,
                              int* __restrict__ tok_of_slot, float* __restrict__ wt_of_slot,
                              int* __restrict__ slot_of) {
  int i = blockIdx.x * 256 + threadIdx.x;
  if (i >= Ttok * TOPK) return;
  int e = sel_e[i];
  int t = i / TOPK;
  int pos = atomicAdd(&fill[e], 1);
  int slot = pbase[e] + pos;
  tok_of_slot[slot] = t;
  wt_of_slot[slot] = sel_w[i];
  slot_of[i] = slot;
}

// --------------------------- gate+up fused GEMM -----------------------------
// act[row][col] = silu(A@G^T)*(A@U^T)*rowscale.  BM=256, BN=64 per matmul,
// BK=32.  Single LDS buffer, stage -> sync -> compute -> sync.
// Bank swizzle (rule 21): stage thread (srow, c=tid&3) fetches global 16B
// chunk c ^ ((srow>>1)&3) into LINEAR LDS slot c; readers XOR quad the same.

__global__ __launch_bounds__(256, 2)
void gateup_kernel(const bf16* __restrict__ Abase,
                   const bf16* __restrict__ w1b, const bf16* __restrict__ sw1b,
                   bf16* __restrict__ actx, bf16* __restrict__ acts,
                   const int* __restrict__ tok_of_slot, const float* __restrict__ wt_of_slot,
                   const int* __restrict__ pbase, const int* __restrict__ mtiles) {
  constexpr int BM = BMT;
  constexpr int NQ = BM / 64;        // 4 64-row staging chunks of A
  constexpr int WROWS = BM / 4;      // 64 rows per wave
  constexpr int NI = WROWS / 16;     // 4
  constexpr int K = Hdim;

  // XCD-chunked swizzle: dispatch d -> logical l; logical order is mt-fastest
  // so the (<=8) M-tile siblings sharing one B panel sit in one XCD chunk.
  const int l = ((int)blockIdx.x & 7) * GU_CHNK + ((int)blockIdx.x >> 3);
  bool SH; int e = 0, xt, mt;
  if (l < GU_R) {
    SH = false;
    e = l / 176; int r = l - e * 176;        // 176 = 22 x-tiles * 8 mt
    xt = r >> 3; mt = r & 7;
    if (mt >= mtiles[e]) return;
  } else {
    SH = true;
    int ls = l - GU_R;                       // 352 = 44 x-tiles * 8 mt
    xt = ls >> 3; mt = ls & 7;
  }
  const bf16* Wb; bf16* C; int Isz, row0;
  if (SH) { Wb = sw1b; C = acts; Isz = ISdim; row0 = mt * BM; }
  else    { Wb = w1b + (size_t)e * 2 * Idim * Hdim; C = actx; Isz = Idim;
            row0 = pbase[e] + mt * BM; }
  const int col0 = xt * 64;

  const int tid = threadIdx.x;
  const int lane = tid & 63;
  const int wv = tid >> 6;
  const int m16 = lane & 15, quad = lane >> 4;

  __shared__ __align__(16) bf16 ldsA[BM * 32];
  __shared__ __align__(16) bf16 ldsG[64 * 32];
  __shared__ __align__(16) bf16 ldsU[64 * 32];

  const int srow = tid >> 2;                              // 0..63
  const int scol = ((tid & 3) ^ ((srow >> 1) & 3)) * 8;   // inverse bank swizzle

  const bf16* aptr[NQ];
#pragma unroll
  for (int q = 0; q < NQ; q++) {
    int r = row0 + q * 64 + srow;
    int tok = SH ? r : tok_of_slot[r];
    if (tok < 0) tok = 0;            // pad slot: rowscale==0 zeroes its act
    aptr[q] = Abase + (size_t)tok * K + scol;
  }
  const bf16* gptr = Wb + (size_t)(col0 + srow) * K + scol;
  const bf16* uptr = Wb + (size_t)(Isz + col0 + srow) * K + scol;

  f32x4 accg[NI][4], accu[NI][4];
#pragma unroll
  for (int i = 0; i < NI; i++)
#pragma unroll
    for (int j = 0; j < 4; j++)
#pragma unroll
      for (int r = 0; r < 4; r++) { accg[i][j][r] = 0.f; accu[i][j][r] = 0.f; }

  const int qsw8 = (quad ^ ((m16 >> 1) & 3)) * 8;   // read-side bank swizzle

  for (int k0 = 0; k0 < K; k0 += 32) {
    gll16(gptr + k0, &ldsG[tid * 8]);
    gll16(uptr + k0, &ldsU[tid * 8]);
#pragma unroll
    for (int q = 0; q < NQ; q++) gll16(aptr[q] + k0, &ldsA[q * 2048 + tid * 8]);
    __syncthreads();
    bf16x8 af[NI], gf[4], uf[4];
#pragma unroll
    for (int i = 0; i < NI; i++)
      af[i] = *(const bf16x8*)(&ldsA[(wv * WROWS + i * 16 + m16) * 32 + qsw8]);
#pragma unroll
    for (int j = 0; j < 4; j++) {
      gf[j] = *(const bf16x8*)(&ldsG[(j * 16 + m16) * 32 + qsw8]);
      uf[j] = *(const bf16x8*)(&ldsU[(j * 16 + m16) * 32 + qsw8]);
    }
#pragma unroll
    for (int i = 0; i < NI; i++)
#pragma unroll
      for (int j = 0; j < 4; j++) {
        accg[i][j] = __builtin_amdgcn_mfma_f32_16x16x32_bf16(af[i], gf[j], accg[i][j], 0, 0, 0);
        accu[i][j] = __builtin_amdgcn_mfma_f32_16x16x32_bf16(af[i], uf[j], accu[i][j], 0, 0, 0);
      }
    __syncthreads();
  }

#pragma unroll
  for (int i = 0; i < NI; i++) {
#pragma unroll
    for (int r = 0; r < 4; r++) {
      int grow = row0 + wv * WROWS + i * 16 + quad * 4 + r;
      float scale = SH ? 1.f : wt_of_slot[grow];
#pragma unroll
      for (int j = 0; j < 4; j++) {
        float g = accg[i][j][r];
        float u = accu[i][j][r];
        float a = g * u * scale / (1.f + __expf(-g));   // silu(g)*u*scale
        C[(size_t)grow * Isz + (col0 + j * 16 + m16)] = (bf16)a;
      }
    }
  }
}

// --------------------------- down-proj GEMM ---------------------------------
// BM=256, BN=128, BK=32; single-buffer loop + same swizzles.
// Routed: plain store to slot_out[slot][H]; shared: plain store to out[t][H].

__global__ __launch_bounds__(256, 2)
void down_kernel(const bf16* __restrict__ actx, const bf16* __restrict__ acts,
                 const bf16* __restrict__ w2b, const bf16* __restrict__ sw2b,
                 float* __restrict__ slot_out, float* __restrict__ out,
                 const int* __restrict__ pbase, const int* __restrict__ mtiles) {
  constexpr int BM = BMT;
  constexpr int NQ = BM / 64;
  constexpr int WROWS = BM / 4;
  constexpr int NI = WROWS / 16;

  const int l = ((int)blockIdx.x & 7) * DN_CHNK + ((int)blockIdx.x >> 3);
  bool SH; int e = 0, xt, mt;
  if (l < DN_R) {
    SH = false;
    e = l >> 7; int r = l & 127;             // 128 = 16 x-tiles * 8 mt
    xt = r >> 3; mt = r & 7;
    if (mt >= mtiles[e]) return;
  } else {
    SH = true;
    int ls = l - DN_R;                       // 128 = 16 x-tiles * 8 mt
    xt = ls >> 3; mt = ls & 7;
  }
  const bf16* A; const bf16* Wb; float* dst; int K, row0;
  if (SH) { A = acts; Wb = sw2b; dst = out; K = ISdim; row0 = mt * BM; }
  else    { A = actx; Wb = w2b + (size_t)e * Hdim * Idim; dst = slot_out; K = Idim;
            row0 = pbase[e] + mt * BM; }
  const int col0 = xt * 128;

  const int tid = threadIdx.x;
  const int lane = tid & 63;
  const int wv = tid >> 6;
  const int m16 = lane & 15, quad = lane >> 4;

  __shared__ __align__(16) bf16 ldsA[BM * 32];
  __shared__ __align__(16) bf16 ldsB[128 * 32];

  const int srow = tid >> 2;
  const int scol = ((tid & 3) ^ ((srow >> 1) & 3)) * 8;

  const bf16* aptr[NQ];
#pragma unroll
  for (int q = 0; q < NQ; q++)
    aptr[q] = A + (size_t)(row0 + q * 64 + srow) * K + scol;
  const bf16* bptr[2];
#pragma unroll
  for (int q = 0; q < 2; q++)
    bptr[q] = Wb + (size_t)(col0 + q * 64 + srow) * K + scol;

  f32x4 acc[NI][8];
#pragma unroll
  for (int i = 0; i < NI; i++)
#pragma unroll
    for (int j = 0; j < 8; j++)
#pragma unroll
      for (int r = 0; r < 4; r++) acc[i][j][r] = 0.f;

  const int qsw8 = (quad ^ ((m16 >> 1) & 3)) * 8;

  for (int k0 = 0; k0 < K; k0 += 32) {
#pragma unroll
    for (int q = 0; q < 2; q++) gll16(bptr[q] + k0, &ldsB[q * 2048 + tid * 8]);
#pragma unroll
    for (int q = 0; q < NQ; q++) gll16(aptr[q] + k0, &ldsA[q * 2048 + tid * 8]);
    __syncthreads();
    bf16x8 af[NI], bfr[8];
#pragma unroll
    for (int i = 0; i < NI; i++)
      af[i] = *(const bf16x8*)(&ldsA[(wv * WROWS + i * 16 + m16) * 32 + qsw8]);
#pragma unroll
    for (int j = 0; j < 8; j++)
      bfr[j] = *(const bf16x8*)(&ldsB[(j * 16 + m16) * 32 + qsw8]);
#pragma unroll
    for (int i = 0; i < NI; i++)
#pragma unroll
      for (int j = 0; j < 8; j++)
        acc[i][j] = __builtin_amdgcn_mfma_f32_16x16x32_bf16(af[i], bfr[j], acc[i][j], 0, 0, 0);
    __syncthreads();
  }

#pragma unroll
  for (int i = 0; i < NI; i++) {
#pragma unroll
    for (int r = 0; r < 4; r++) {
      int grow = row0 + wv * WROWS + i * 16 + quad * 4 + r;
      float* orow = dst + (size_t)grow * Hdim;   // slot row (routed) or token row (shared)
#pragma unroll
      for (int j = 0; j < 8; j++) orow[col0 + j * 16 + m16] = acc[i][j][r];
    }
  }
}

// --------------------------- combine ----------------------------------------
// out[t] (already holds shared-path result) += sum_k slot_out[slot_of[t][k]].

__global__ void combine_kernel(const float* __restrict__ slot_out,
                               const int* __restrict__ slot_of,
                               float* __restrict__ out) {
  const int t = blockIdx.x;
  const int c = threadIdx.x * 8;
  float* op = out + (size_t)t * Hdim + c;
  f32x4 a0 = *(const f32x4*)op;
  f32x4 a1 = *(const f32x4*)(op + 4);
#pragma unroll
  for (int k = 0; k < TOPK; k++) {
    int s = slot_of[t * TOPK + k];
    const float* sp = slot_out + (size_t)s * Hdim + c;
    f32x4 b0 = *(const f32x4*)sp;
    f32x4 b1 = *(const f32x4*)(sp + 4);
    a0 += b0; a1 += b1;
  }
  *(f32x4*)op = a0;
  *(f32x4*)(op + 4) = a1;
}

// --------------------------- launch ----------------------------------------

extern "C" void kernel_launch(void* const* d_in, const int* in_sizes, int n_in,
                              void* d_out, int out_size, void* d_ws, size_t ws_size,
                              hipStream_t stream) {
  (void)in_sizes; (void)n_in; (void)out_size; (void)ws_size;
  const float* x   = (const float*)d_in[0];
  const float* gw  = (const float*)d_in[1];
  const float* w1  = (const float*)d_in[2];
  const float* w2  = (const float*)d_in[3];
  const float* sw1 = (const float*)d_in[4];
  const float* sw2 = (const float*)d_in[5];
  float* out = (float*)d_out;

  char* ws = (char*)d_ws;
  size_t off = 0;
  auto alloc = [&](size_t bytes) -> void* {
    void* p = ws + off;
    off += (bytes + 255) & ~(size_t)255;
    return p;
  };
  int*   cnt   = (int*)alloc(NE * 4);
  int*   fill  = (int*)alloc(NE * 4);
  int*   pbase = (int*)alloc(NE * 4);
  int*   mtl   = (int*)alloc(NE * 4);
  int*   sel_e = (int*)alloc((size_t)Ttok * TOPK * 4);
  float* sel_w = (float*)alloc((size_t)Ttok * TOPK * 4);
  int*   slotf = (int*)alloc((size_t)Ttok * TOPK * 4);
  int*   tok   = (int*)alloc((size_t)MAX_SLOTS * 4);
  float* wt    = (float*)alloc((size_t)MAX_SLOTS * 4);
  bf16*  xb    = (bf16*)alloc((size_t)Ttok * Hdim * 2);
  bf16*  actx  = (bf16*)alloc((size_t)MAX_SLOTS * Idim * 2);   // expert activations
  bf16*  acts  = (bf16*)alloc((size_t)Ttok * ISdim * 2);       // shared activations

  const size_t n_w1  = (size_t)NE * 2 * Idim * Hdim;   // 92.3M
  const size_t n_w2  = (size_t)NE * Hdim * Idim;       // 46.1M
  const size_t n_sw1 = (size_t)2 * ISdim * Hdim;       // 11.5M
  const size_t n_sw2 = (size_t)Hdim * ISdim;           // 5.8M
  bf16* w1b  = (bf16*)alloc(n_w1 * 2);    // 184.6 MB
  bf16* w2b  = (bf16*)alloc(n_w2 * 2);
  bf16* sw1b = (bf16*)alloc(n_sw1 * 2);
  bf16* sw2b = (bf16*)alloc(n_sw2 * 2);
  // slot_out (MAX_SLOTS x H fp32 = 134 MB) aliases w1b (184.6 MB): w1b is dead
  // after the gateup launch; the down launch writing slot_out is in-stream after.
  float* slot_out = (float*)w1b;

  init_kernel<<<(MAX_SLOTS + 255) / 256, 256, 0, stream>>>(cnt, fill, tok, wt);
  cvt_kernel<<<((int)(Ttok * (size_t)Hdim / 8) + 255) / 256, 256, 0, stream>>>(x, xb, Ttok * Hdim / 8);
  router_kernel<<<Ttok, 64, 0, stream>>>(x, gw, sel_e, sel_w, cnt);
  scan_kernel<<<1, 64, 0, stream>>>(cnt, pbase, mtl);
  assign_kernel<<<(Ttok * TOPK + 255) / 256, 256, 0, stream>>>(sel_e, sel_w, pbase, fill, tok, wt, slotf);

  cvt_kernel<<<((int)(n_w1 / 8) + 255) / 256, 256, 0, stream>>>(w1, w1b, (int)(n_w1 / 8));
  cvt_kernel<<<((int)(n_w2 / 8) + 255) / 256, 256, 0, stream>>>(w2, w2b, (int)(n_w2 / 8));
  cvt_kernel<<<((int)(n_sw1 / 8) + 255) / 256, 256, 0, stream>>>(sw1, sw1b, (int)(n_sw1 / 8));
  cvt_kernel<<<((int)(n_sw2 / 8) + 255) / 256, 256, 0, stream>>>(sw2, sw2b, (int)(n_sw2 / 8));

  gateup_kernel<<<GU_GRID, 256, 0, stream>>>(xb, w1b, sw1b, actx, acts, tok, wt, pbase, mtl);
  down_kernel<<<DN_GRID, 256, 0, stream>>>(actx, acts, w2b, sw2b, slot_out, out, pbase, mtl);
  combine_kernel<<<Ttok, Hdim / 8, 0, stream>>>(slot_out, slotf, out);
}